// Round 11
// baseline (2117.129 us; speedup 1.0000x reference)
//
#include <hip/hip_runtime.h>

// ErosionLayer: B=16, W=512, ITERS=10, fp32. PASSING numeric recipe
// (r5/r6/r8/r9/r10, absmax 0.02734375): XLA-style greedy FMA via explicit
// fmaf() at exact sites, contract(off) elsewhere, correctly-rounded fp32
// div/sqrt. DO NOT change op order or fusion sites.
//
// r11: HYPOTHESIS TEST. r5..r10 all benched ~440 us despite wildly different
// structures; suspect hipLaunchCooperativeKernel fails under hipGraph capture
// -> silent fallback meant every timed graph was the r6 sequence. This round:
// r9's mega kernel (256 blk x 1024 thr x 16 cells, s/w/v register-resident,
// 64 VGPR) launched as a NORMAL kernel with a software grid barrier
// (per-step counters in ws, agent-scope atomics, threadfence rel/acq) —
// fully capturable, no fallback. Deadlock-safe: launch_bounds(1024,4) caps
// VGPR<=128 => >=1 block/CU x 256 CUs >= 256 blocks co-resident.
#pragma clang fp contract(off)

constexpr int WW    = 512;
constexpr int NPIX  = WW * WW;       // 2^18
constexpr int NTOT  = 16 * NPIX;     // 4194304
constexpr int MTHR  = 1024;
constexpr int CELLS = 16;
constexpr int NBLK  = NTOT / (MTHR * CELLS);   // 256
constexpr int NBAR  = 16;            // barrier counters (10 used)

struct Args {
    const float* in_terr;
    float*       T0;      // d_out: final output
    float*       T1;      // ws
    unsigned*    cnt;     // ws: NBAR barrier counters (zeroed by init kernel)
    const float* rain;    // (10, W, W)
    const float* gno;     // (10, W, W)
    const float* p_rr; const float* p_evap; const float* p_minhd;
    const float* p_heps; const float* p_grav; const float* p_scc;
    const float* p_diss; const float* p_depo;
};

__device__ __forceinline__ void grid_barrier(unsigned* cnt)
{
    __threadfence();                      // release this thread's stores
    __syncthreads();
    if (threadIdx.x == 0) {
        __hip_atomic_fetch_add(cnt, 1u, __ATOMIC_ACQ_REL, __HIP_MEMORY_SCOPE_AGENT);
        while (__hip_atomic_load(cnt, __ATOMIC_ACQUIRE, __HIP_MEMORY_SCOPE_AGENT)
               < (unsigned)NBLK) {
            __builtin_amdgcn_s_sleep(8);
        }
    }
    __syncthreads();
    __threadfence();                      // acquire other blocks' stores
}

__global__ __launch_bounds__(64) void barrier_init(unsigned* cnt)
{
    if (threadIdx.x < NBAR) cnt[threadIdx.x] = 0u;
}

__global__ __launch_bounds__(MTHR, 4) void erosion_mega(Args a)
{
    #pragma clang fp contract(off)
    const float CELLW = 0.390625f;        // 200/512, exact

    const int base = blockIdx.x * (MTHR * CELLS) + threadIdx.x;

    float rr    = fmaxf(a.p_rr[0], 0.0f);
    float evapr = fmaxf(a.p_evap[0], 0.0f);
    float minhd = a.p_minhd[0];
    float heps  = a.p_heps[0];
    float gravr = fmaxf(a.p_grav[0], 0.0f);
    float sccr  = fmaxf(a.p_scc[0], 0.0f);
    float diss  = a.p_diss[0];
    float depo  = a.p_depo[0];

    float sA[CELLS], wA[CELLS], vA[CELLS];
    #pragma unroll
    for (int k = 0; k < CELLS; ++k) {
        int idx = base + k * MTHR;
        a.T0[idx] = (1.0f - a.in_terr[idx]) / 2.0f;
        sA[k] = 0.0f; wA[k] = 0.0f; vA[k] = 0.0f;
    }
    grid_barrier(a.cnt + 0);

    #pragma unroll 1
    for (int it = 0; it < 10; ++it) {
        const float* tin  = (it & 1) ? a.T1 : a.T0;
        float*       tout = (it & 1) ? a.T0 : a.T1;
        const float* rain = a.rain + it * NPIX;
        const float* gno  = a.gno  + it * NPIX;
        const bool   fin  = (it == 9);

        #pragma unroll
        for (int k = 0; k < CELLS; ++k) {
            int idx = base + k * MTHR;
            int rem = idx & (NPIX - 1);
            int r   = rem >> 9;
            int c   = rem & (WW - 1);
            const float* tb = tin + (idx - rem);

            float t_c = tb[rem];

            // FROZEN r5/r6 math — exact op order & fusion sites.
            float w = fmaf(rr, rain[rem], wA[k]);

            float dx, dy;
            if      (r == 0)      dx = 0.5f * fmaf(t_c, 1.1f, -t_c);
            else if (r == WW - 1) dx = 0.5f * fmaf(t_c, 0.9f, -t_c);
            else                  dx = 0.5f * (tb[rem + WW] - tb[rem - WW]);
            if      (c == 0)      dy = 0.5f * fmaf(t_c, 1.1f, -t_c);
            else if (c == WW - 1) dy = 0.5f * fmaf(t_c, 0.9f, -t_c);
            else                  dy = 0.5f * (tb[rem + 1] - tb[rem - 1]);

            float mag = sqrtf(fmaf(dx, dx, dy * dy) + 1e-11f);
            float rX  = gno[rem];
            float rY  = sqrtf(fmaf(-rX, rX, 1.0f));   // 1 - rX*rX -> fnma
            float factor = fmaxf(1e-10f - mag, 0.0f); // always 0; fidelity
            float den = mag + factor;
            float fdx = fmaf(factor, rX, dx) / den;
            float fdy = fmaf(factor, rY, dy) / den;

            float fx  = (float)c + (-fdx);
            float fy  = (float)r + (-fdy);
            float x0f = floorf(fx), y0f = floorf(fy);
            float wx1 = fx - x0f;
            float wy1 = fy - y0f;
            int x0 = (int)x0f, y0 = (int)y0f;
            int x1 = x0 + 1,   y1 = y0 + 1;

            bool vx0 = (x0 >= 0) & (x0 < WW);
            bool vx1 = (x1 >= 0) & (x1 < WW);
            bool vy0 = (y0 >= 0) & (y0 < WW);
            bool vy1 = (y1 >= 0) & (y1 < WW);
            int x0c = min(max(x0, 0), WW - 1), x1c = min(max(x1, 0), WW - 1);
            int y0c = min(max(y0, 0), WW - 1), y1c = min(max(y1, 0), WW - 1);

            float g00 = (vx0 && vy0) ? (tb[y0c * WW + x0c] - 1.0f) : 0.0f;
            float g10 = (vx1 && vy0) ? (tb[y0c * WW + x1c] - 1.0f) : 0.0f;
            float g01 = (vx0 && vy1) ? (tb[y1c * WW + x0c] - 1.0f) : 0.0f;
            float g11 = (vx1 && vy1) ? (tb[y1c * WW + x1c] - 1.0f) : 0.0f;

            float wx0 = 1.0f - wx1;
            float wy0 = 1.0f - wy1;
            float rowA = fmaf(wx0, g00, wx1 * g10);
            float rowB = fmaf(wx0, g01, wx1 * g11);
            float bil  = fmaf(wy0, rowA, wy1 * rowB);
            float neighbor = bil + 1.0f;

            float hd = t_c - neighbor;

            float v = vA[k];
            float s = sA[k];

            float hds  = ((hd - heps) > 0.0f) ? 1.0f : 0.0f;  // sign(relu(hd-eps))
            float nhd  = hds * fmaxf(hd, minhd);
            float q1 = nhd / CELLW;
            float q2 = q1 * v;
            float q3 = q2 * w;
            float sdiff = fmaf(-q3, sccr, s);                 // s - sed_cap
            float ftb   = (hd < 0.0f) ? 1.0f : 0.0f;          // relu(sign(-hd))
            float first = fminf(fmaxf(-hd, 0.0f), s);
            float ra = fmaxf(sdiff * depo, 0.0f);
            float rb = fmaxf((-sdiff) * diss, 0.0f);
            float deparg = fmaf(1.0f - ftb, ra - rb, first);
            float dep    = fmaxf(-fmaxf(hd, 0.0f), deparg);

            float s_new = s - dep;
            float t_new = t_c + dep;

            float rn = fmaxf(-fdy, 0.0f);
            float rm = fmaxf(1.0f - fabsf(fdy), 0.0f);
            float rp = fmaxf(fdy, 0.0f);

            float s1 = (c == WW - 1) ? 0.0f : rn * s_new;
            float s3 = (c == 0)      ? 0.0f : rp * s_new;
            sA[k] = fmaf(rm, s_new, s1) + s3;

            float w1 = (c == WW - 1) ? 0.0f : rn * w;
            float w3 = (c == 0)      ? 0.0f : rp * w;
            float wd = fmaf(rm, w, w1) + w3;
            wA[k] = wd * (1.0f - evapr);

            vA[k] = (gravr * hd) / CELLW;

            if (fin) {
                float aa = fmaf(-t_new, 2.0f, 1.0f);          // 1 - t*2 -> fnma
                float bq = 1.0f + aa;
                tout[idx] = fmaxf(bq, 0.0f) - 1.0f;
            } else {
                tout[idx] = t_new;
            }
        }

        if (it != 9) grid_barrier(a.cnt + 1 + it);
    }
}

extern "C" void kernel_launch(void* const* d_in, const int* in_sizes, int n_in,
                              void* d_out, int out_size, void* d_ws, size_t ws_size,
                              hipStream_t stream) {
    Args a;
    a.in_terr = (const float*)d_in[0];
    a.rain    = (const float*)d_in[1];
    a.gno     = (const float*)d_in[2];
    a.p_rr    = (const float*)d_in[3];
    a.p_evap  = (const float*)d_in[4];
    a.p_minhd = (const float*)d_in[5];
    a.p_heps  = (const float*)d_in[6];
    a.p_grav  = (const float*)d_in[7];
    a.p_scc   = (const float*)d_in[8];
    a.p_diss  = (const float*)d_in[9];
    a.p_depo  = (const float*)d_in[10];
    a.T0      = (float*)d_out;
    a.T1      = (float*)d_ws;
    a.cnt     = (unsigned*)((float*)d_ws + (size_t)NTOT);

    barrier_init<<<1, 64, 0, stream>>>(a.cnt);
    erosion_mega<<<dim3(NBLK), dim3(MTHR), 0, stream>>>(a);
}

// Round 12
// 440.547 us; speedup vs baseline: 4.8057x; 4.8057x over previous
//
#include <hip/hip_runtime.h>

// ErosionLayer: B=16, W=512, ITERS=10, fp32. PASSING numeric recipe (r5..r11,
// absmax 0.02734375): XLA-style greedy FMA via explicit fmaf() at exact sites,
// contract(off) elsewhere, correctly-rounded fp32 div/sqrt. DO NOT change op
// order or fusion sites.
//
// r12: structure verdict from r11 — coop/persistent megakernels lose on this
// chip (coop launch fails under graph capture -> r8/r9 timed the r6 fallback;
// true mega costs 703-2077 us vs r6's 442). Keep the 11-dispatch structure,
// make the step kernel BW-shaped: 4 cells/thread, float4 loads/stores for all
// streaming arrays (terr rows, rain, gno, sed/wat/vel), 16 independent scalar
// gathers/thread (L1-resident: window is inside the rows already loaded).
// Same loads, same arithmetic, same order => bit-identical trajectory.
#pragma clang fp contract(off)

constexpr int WW   = 512;
constexpr int NPIX = WW * WW;      // 2^18
constexpr int NTOT = 16 * NPIX;    // 4194304

__global__ __launch_bounds__(256) void erosion_init4(
    const float* __restrict__ in, float* __restrict__ terr,
    float* __restrict__ sed, float* __restrict__ wat, float* __restrict__ vel)
{
    #pragma clang fp contract(off)
    int gid  = blockIdx.x * 256 + threadIdx.x;
    int idx0 = gid * 4;
    float4 i4 = *(const float4*)(in + idx0);
    float4 t4;
    t4.x = (1.0f - i4.x) / 2.0f;
    t4.y = (1.0f - i4.y) / 2.0f;
    t4.z = (1.0f - i4.z) / 2.0f;
    t4.w = (1.0f - i4.w) / 2.0f;
    *(float4*)(terr + idx0) = t4;
    float4 z4 = make_float4(0.0f, 0.0f, 0.0f, 0.0f);
    *(float4*)(sed + idx0) = z4;
    *(float4*)(wat + idx0) = z4;
    *(float4*)(vel + idx0) = z4;
}

__global__ __launch_bounds__(256, 2) void erosion_step4(
    const float* __restrict__ terr_in, float* __restrict__ terr_out,
    float* __restrict__ sed, float* __restrict__ wat, float* __restrict__ vel,
    const float* __restrict__ rain, const float* __restrict__ gnoise,
    const float* __restrict__ s_rain_rate, const float* __restrict__ s_evap,
    const float* __restrict__ s_minhd, const float* __restrict__ s_heps,
    const float* __restrict__ s_grav, const float* __restrict__ s_scc,
    const float* __restrict__ s_diss, const float* __restrict__ s_depo,
    int final_flag)
{
    #pragma clang fp contract(off)
    const float CELLW = 0.390625f;          // 200/512, exact

    int gid  = blockIdx.x * 256 + threadIdx.x;
    int idx0 = gid * 4;                     // first of 4 consecutive cells
    int rem0 = idx0 & (NPIX - 1);
    int r    = rem0 >> 9;
    int c0   = rem0 & (WW - 1);             // multiple of 4
    const float* tb = terr_in + (idx0 - rem0);

    float rr    = fmaxf(s_rain_rate[0], 0.0f);
    float evapr = fmaxf(s_evap[0], 0.0f);
    float minhd = s_minhd[0];
    float heps  = s_heps[0];
    float gravr = fmaxf(s_grav[0], 0.0f);
    float sccr  = fmaxf(s_scc[0], 0.0f);
    float diss  = s_diss[0];
    float depo  = s_depo[0];

    // ---- streaming loads (independent, issued up front) ----
    float4 tc4 = *(const float4*)(tb + rem0);
    int rup = (r == 0)      ? 0        : r - 1;
    int rdn = (r == WW - 1) ? WW - 1   : r + 1;
    float4 tu4 = *(const float4*)(tb + rup * WW + c0);   // unused values at r=0 (formula path)
    float4 td4 = *(const float4*)(tb + rdn * WW + c0);
    float  tl  = (c0 > 0)        ? tb[rem0 - 1] : 0.0f;  // dy left edge of the quad
    float  trr = (c0 < WW - 4)   ? tb[rem0 + 4] : 0.0f;  // dy right edge of the quad
    float4 rain4 = *(const float4*)(rain   + rem0);
    float4 gno4  = *(const float4*)(gnoise + rem0);
    float4 s4 = *(const float4*)(sed + idx0);
    float4 w4 = *(const float4*)(wat + idx0);
    float4 v4 = *(const float4*)(vel + idx0);

    float tcv[4]  = { tc4.x, tc4.y, tc4.z, tc4.w };
    float tuv[4]  = { tu4.x, tu4.y, tu4.z, tu4.w };
    float tdv[4]  = { td4.x, td4.y, td4.z, td4.w };
    float rainv[4]= { rain4.x, rain4.y, rain4.z, rain4.w };
    float gnov[4] = { gno4.x, gno4.y, gno4.z, gno4.w };
    float sv[4]   = { s4.x, s4.y, s4.z, s4.w };
    float wv[4]   = { w4.x, w4.y, w4.z, w4.w };
    float vv[4]   = { v4.x, v4.y, v4.z, v4.w };

    float tno[4], sno[4], wno[4], vno[4];

    #pragma unroll
    for (int j = 0; j < 4; ++j) {
        const int c = c0 + j;
        float t_c = tcv[j];

        // FROZEN r5/r6 math — exact op order & fusion sites.
        float w = fmaf(rr, rainv[j], wv[j]);

        float dx, dy;
        if      (r == 0)      dx = 0.5f * fmaf(t_c, 1.1f, -t_c);
        else if (r == WW - 1) dx = 0.5f * fmaf(t_c, 0.9f, -t_c);
        else                  dx = 0.5f * (tdv[j] - tuv[j]);
        float left  = (j == 0) ? tl  : tcv[j - 1];
        float right = (j == 3) ? trr : tcv[j + 1];
        if      (c == 0)      dy = 0.5f * fmaf(t_c, 1.1f, -t_c);
        else if (c == WW - 1) dy = 0.5f * fmaf(t_c, 0.9f, -t_c);
        else                  dy = 0.5f * (right - left);

        float mag = sqrtf(fmaf(dx, dx, dy * dy) + 1e-11f);
        float rX  = gnov[j];
        float rY  = sqrtf(fmaf(-rX, rX, 1.0f));   // 1 - rX*rX -> fnma
        float factor = fmaxf(1e-10f - mag, 0.0f); // always 0; fidelity
        float den = mag + factor;
        float fdx = fmaf(factor, rX, dx) / den;   // |fdx| <= 1
        float fdy = fmaf(factor, rY, dy) / den;   // |fdy| <= 1

        float fx  = (float)c + (-fdx);
        float fy  = (float)r + (-fdy);
        float x0f = floorf(fx), y0f = floorf(fy);
        float wx1 = fx - x0f;
        float wy1 = fy - y0f;
        int x0 = (int)x0f, y0 = (int)y0f;
        int x1 = x0 + 1,   y1 = y0 + 1;

        bool vx0 = (x0 >= 0) & (x0 < WW);
        bool vx1 = (x1 >= 0) & (x1 < WW);
        bool vy0 = (y0 >= 0) & (y0 < WW);
        bool vy1 = (y1 >= 0) & (y1 < WW);
        int x0c = min(max(x0, 0), WW - 1), x1c = min(max(x1, 0), WW - 1);
        int y0c = min(max(y0, 0), WW - 1), y1c = min(max(y1, 0), WW - 1);

        // L1-resident gathers (window within rows r-1..r+1 just streamed)
        float g00 = (vx0 && vy0) ? (tb[y0c * WW + x0c] - 1.0f) : 0.0f;
        float g10 = (vx1 && vy0) ? (tb[y0c * WW + x1c] - 1.0f) : 0.0f;
        float g01 = (vx0 && vy1) ? (tb[y1c * WW + x0c] - 1.0f) : 0.0f;
        float g11 = (vx1 && vy1) ? (tb[y1c * WW + x1c] - 1.0f) : 0.0f;

        float wx0 = 1.0f - wx1;
        float wy0 = 1.0f - wy1;
        float rowA = fmaf(wx0, g00, wx1 * g10);
        float rowB = fmaf(wx0, g01, wx1 * g11);
        float bil  = fmaf(wy0, rowA, wy1 * rowB);
        float neighbor = bil + 1.0f;

        float hd = t_c - neighbor;

        float v = vv[j];
        float s = sv[j];

        float hds  = ((hd - heps) > 0.0f) ? 1.0f : 0.0f;  // sign(relu(hd-eps))
        float nhd  = hds * fmaxf(hd, minhd);
        float q1 = nhd / CELLW;
        float q2 = q1 * v;
        float q3 = q2 * w;
        float sdiff = fmaf(-q3, sccr, s);                 // s - sed_cap
        float ftb   = (hd < 0.0f) ? 1.0f : 0.0f;          // relu(sign(-hd))
        float first = fminf(fmaxf(-hd, 0.0f), s);
        float ra = fmaxf(sdiff * depo, 0.0f);
        float rb = fmaxf((-sdiff) * diss, 0.0f);
        float deparg = fmaf(1.0f - ftb, ra - rb, first);
        float dep    = fmaxf(-fmaxf(hd, 0.0f), deparg);

        float s_new = s - dep;
        float t_new = t_c + dep;

        float rn = fmaxf(-fdy, 0.0f);
        float rm = fmaxf(1.0f - fabsf(fdy), 0.0f);
        float rp = fmaxf(fdy, 0.0f);

        float s1 = (c == WW - 1) ? 0.0f : rn * s_new;
        float s3 = (c == 0)      ? 0.0f : rp * s_new;
        sno[j] = fmaf(rm, s_new, s1) + s3;

        float w1 = (c == WW - 1) ? 0.0f : rn * w;
        float w3 = (c == 0)      ? 0.0f : rp * w;
        float wd = fmaf(rm, w, w1) + w3;
        wno[j] = wd * (1.0f - evapr);

        vno[j] = (gravr * hd) / CELLW;

        if (final_flag) {
            float aa = fmaf(-t_new, 2.0f, 1.0f);          // 1 - t*2 -> fnma
            float bq = 1.0f + aa;
            tno[j] = fmaxf(bq, 0.0f) - 1.0f;
        } else {
            tno[j] = t_new;
        }
    }

    *(float4*)(terr_out + idx0) = make_float4(tno[0], tno[1], tno[2], tno[3]);
    *(float4*)(sed + idx0)      = make_float4(sno[0], sno[1], sno[2], sno[3]);
    *(float4*)(wat + idx0)      = make_float4(wno[0], wno[1], wno[2], wno[3]);
    *(float4*)(vel + idx0)      = make_float4(vno[0], vno[1], vno[2], vno[3]);
}

extern "C" void kernel_launch(void* const* d_in, const int* in_sizes, int n_in,
                              void* d_out, int out_size, void* d_ws, size_t ws_size,
                              hipStream_t stream) {
    const float* in_terr    = (const float*)d_in[0];
    const float* rain_all   = (const float*)d_in[1];  // (1,10,W,W)
    const float* gnoise_all = (const float*)d_in[2];  // (1,10,W,W)
    const float* p_rr       = (const float*)d_in[3];
    const float* p_evap     = (const float*)d_in[4];
    const float* p_minhd    = (const float*)d_in[5];
    const float* p_heps     = (const float*)d_in[6];
    const float* p_grav     = (const float*)d_in[7];
    const float* p_scc      = (const float*)d_in[8];
    const float* p_diss     = (const float*)d_in[9];
    const float* p_depo     = (const float*)d_in[10];

    float* T0  = (float*)d_out;          // even-step source; final output
    float* ws  = (float*)d_ws;
    float* T1  = ws;
    float* sed = ws + (size_t)NTOT;
    float* wat = ws + (size_t)2 * NTOT;
    float* vel = ws + (size_t)3 * NTOT;

    dim3 block(256), grid(NTOT / 1024);  // 4 cells/thread
    erosion_init4<<<grid, block, 0, stream>>>(in_terr, T0, sed, wat, vel);

    for (int it = 0; it < 10; ++it) {
        const float* tin  = (it & 1) ? T1 : T0;
        float*       tout = (it & 1) ? T0 : T1;
        erosion_step4<<<grid, block, 0, stream>>>(
            tin, tout, sed, wat, vel,
            rain_all + (size_t)it * NPIX, gnoise_all + (size_t)it * NPIX,
            p_rr, p_evap, p_minhd, p_heps, p_grav, p_scc, p_diss, p_depo,
            (it == 9) ? 1 : 0);
    }
}

// Round 13
// 425.999 us; speedup vs baseline: 4.9698x; 1.0342x over previous
//
#include <hip/hip_runtime.h>

// ErosionLayer: B=16, W=512, ITERS=10, fp32. PASSING numeric recipe (r5..r12,
// absmax 0.02734375): XLA-style greedy FMA via explicit fmaf() at exact sites,
// contract(off) elsewhere, correctly-rounded fp32 div/sqrt. DO NOT change op
// order or fusion sites.
//
// r13: latency/occupancy attack. Evidence: r6 scalar and r12 float4 both run
// steps at ~39 us (3.4 TB/s) while pure fills hit 6.4 TB/s; r9-mega counters
// (same code shape) showed VALUBusy 30%, HBM 10% -> dependent-chain latency
// with too few waves. Changes: (1) __launch_bounds__(256,8): VGPR<=64 (r9
// proved this math fits 16 cells in 64 VGPR; we carry 4) -> 8 waves/SIMD.
// (2) init folded into a specialized step-0 kernel: terrain transform
// (1-in)/2 recomputed per access (bit-identical), s/w/v are +0 literals
// (same bits as reference's zeros) -> saves 134 MB + one dispatch.
#pragma clang fp contract(off)

constexpr int WW   = 512;
constexpr int NPIX = WW * WW;      // 2^18
constexpr int NTOT = 16 * NPIX;    // 4194304

// FROZEN r5/r6 math. TER(g) abstracts the terrain read: step 0 applies the
// init transform on the fly; steps 1..9 read the stored array.
template <bool FIRST>
__device__ __forceinline__ float ter_at(const float* __restrict__ tb, int off)
{
    float v = tb[off];
    if (FIRST) v = (1.0f - v) / 2.0f;
    return v;
}

template <bool FIRST>
__global__ __launch_bounds__(256, 8) void erosion_step4(
    const float* __restrict__ terr_in, float* __restrict__ terr_out,
    float* __restrict__ sed, float* __restrict__ wat, float* __restrict__ vel,
    const float* __restrict__ rain, const float* __restrict__ gnoise,
    const float* __restrict__ s_rain_rate, const float* __restrict__ s_evap,
    const float* __restrict__ s_minhd, const float* __restrict__ s_heps,
    const float* __restrict__ s_grav, const float* __restrict__ s_scc,
    const float* __restrict__ s_diss, const float* __restrict__ s_depo,
    int final_flag)
{
    #pragma clang fp contract(off)
    const float CELLW = 0.390625f;          // 200/512, exact

    int gid  = blockIdx.x * 256 + threadIdx.x;
    int idx0 = gid * 4;                     // 4 consecutive cells
    int rem0 = idx0 & (NPIX - 1);
    int r    = rem0 >> 9;
    int c0   = rem0 & (WW - 1);
    const float* tb = terr_in + (idx0 - rem0);

    float rr    = fmaxf(s_rain_rate[0], 0.0f);
    float evapr = fmaxf(s_evap[0], 0.0f);
    float minhd = s_minhd[0];
    float heps  = s_heps[0];
    float gravr = fmaxf(s_grav[0], 0.0f);
    float sccr  = fmaxf(s_scc[0], 0.0f);
    float diss  = s_diss[0];
    float depo  = s_depo[0];

    // ---- streaming loads (independent, issued up front) ----
    float4 tc4 = *(const float4*)(tb + rem0);
    int rup = (r == 0)      ? 0      : r - 1;
    int rdn = (r == WW - 1) ? WW - 1 : r + 1;
    float4 tu4 = *(const float4*)(tb + rup * WW + c0);
    float4 td4 = *(const float4*)(tb + rdn * WW + c0);
    float  tl  = (c0 > 0)      ? tb[rem0 - 1] : 0.0f;
    float  trr = (c0 < WW - 4) ? tb[rem0 + 4] : 0.0f;
    float4 rain4 = *(const float4*)(rain   + rem0);
    float4 gno4  = *(const float4*)(gnoise + rem0);

    float sv[4], wv[4], vv[4];
    if (FIRST) {
        #pragma unroll
        for (int j = 0; j < 4; ++j) { sv[j] = 0.0f; wv[j] = 0.0f; vv[j] = 0.0f; }
    } else {
        float4 s4 = *(const float4*)(sed + idx0);
        float4 w4 = *(const float4*)(wat + idx0);
        float4 v4 = *(const float4*)(vel + idx0);
        sv[0]=s4.x; sv[1]=s4.y; sv[2]=s4.z; sv[3]=s4.w;
        wv[0]=w4.x; wv[1]=w4.y; wv[2]=w4.z; wv[3]=w4.w;
        vv[0]=v4.x; vv[1]=v4.y; vv[2]=v4.z; vv[3]=v4.w;
    }

    // apply init transform to streamed terrain if FIRST (bit-identical to
    // materializing T0 then reading it back)
    auto xf = [](float x) { return (1.0f - x) / 2.0f; };
    float tcv[4] = { tc4.x, tc4.y, tc4.z, tc4.w };
    float tuv[4] = { tu4.x, tu4.y, tu4.z, tu4.w };
    float tdv[4] = { td4.x, td4.y, td4.z, td4.w };
    if (FIRST) {
        #pragma unroll
        for (int j = 0; j < 4; ++j) {
            tcv[j] = xf(tcv[j]); tuv[j] = xf(tuv[j]); tdv[j] = xf(tdv[j]);
        }
        tl = xf(tl); trr = xf(trr);
    }
    float rainv[4] = { rain4.x, rain4.y, rain4.z, rain4.w };
    float gnov[4]  = { gno4.x,  gno4.y,  gno4.z,  gno4.w };

    float tno[4], sno[4], wno[4], vno[4];

    #pragma unroll
    for (int j = 0; j < 4; ++j) {
        const int c = c0 + j;
        float t_c = tcv[j];

        float w = fmaf(rr, rainv[j], wv[j]);

        float dx, dy;
        if      (r == 0)      dx = 0.5f * fmaf(t_c, 1.1f, -t_c);
        else if (r == WW - 1) dx = 0.5f * fmaf(t_c, 0.9f, -t_c);
        else                  dx = 0.5f * (tdv[j] - tuv[j]);
        float left  = (j == 0) ? tl  : tcv[j - 1];
        float right = (j == 3) ? trr : tcv[j + 1];
        if      (c == 0)      dy = 0.5f * fmaf(t_c, 1.1f, -t_c);
        else if (c == WW - 1) dy = 0.5f * fmaf(t_c, 0.9f, -t_c);
        else                  dy = 0.5f * (right - left);

        float mag = sqrtf(fmaf(dx, dx, dy * dy) + 1e-11f);
        float rX  = gnov[j];
        float rY  = sqrtf(fmaf(-rX, rX, 1.0f));   // 1 - rX*rX -> fnma
        float factor = fmaxf(1e-10f - mag, 0.0f); // always 0; fidelity
        float den = mag + factor;
        float fdx = fmaf(factor, rX, dx) / den;   // |fdx| <= 1
        float fdy = fmaf(factor, rY, dy) / den;   // |fdy| <= 1

        float fx  = (float)c + (-fdx);
        float fy  = (float)r + (-fdy);
        float x0f = floorf(fx), y0f = floorf(fy);
        float wx1 = fx - x0f;
        float wy1 = fy - y0f;
        int x0 = (int)x0f, y0 = (int)y0f;
        int x1 = x0 + 1,   y1 = y0 + 1;

        bool vx0 = (x0 >= 0) & (x0 < WW);
        bool vx1 = (x1 >= 0) & (x1 < WW);
        bool vy0 = (y0 >= 0) & (y0 < WW);
        bool vy1 = (y1 >= 0) & (y1 < WW);
        int x0c = min(max(x0, 0), WW - 1), x1c = min(max(x1, 0), WW - 1);
        int y0c = min(max(y0, 0), WW - 1), y1c = min(max(y1, 0), WW - 1);

        float g00 = (vx0 && vy0) ? (ter_at<FIRST>(tb, y0c * WW + x0c) - 1.0f) : 0.0f;
        float g10 = (vx1 && vy0) ? (ter_at<FIRST>(tb, y0c * WW + x1c) - 1.0f) : 0.0f;
        float g01 = (vx0 && vy1) ? (ter_at<FIRST>(tb, y1c * WW + x0c) - 1.0f) : 0.0f;
        float g11 = (vx1 && vy1) ? (ter_at<FIRST>(tb, y1c * WW + x1c) - 1.0f) : 0.0f;

        float wx0 = 1.0f - wx1;
        float wy0 = 1.0f - wy1;
        float rowA = fmaf(wx0, g00, wx1 * g10);
        float rowB = fmaf(wx0, g01, wx1 * g11);
        float bil  = fmaf(wy0, rowA, wy1 * rowB);
        float neighbor = bil + 1.0f;

        float hd = t_c - neighbor;

        float v = vv[j];
        float s = sv[j];

        float hds  = ((hd - heps) > 0.0f) ? 1.0f : 0.0f;  // sign(relu(hd-eps))
        float nhd  = hds * fmaxf(hd, minhd);
        float q1 = nhd / CELLW;
        float q2 = q1 * v;
        float q3 = q2 * w;
        float sdiff = fmaf(-q3, sccr, s);                 // s - sed_cap
        float ftb   = (hd < 0.0f) ? 1.0f : 0.0f;          // relu(sign(-hd))
        float first = fminf(fmaxf(-hd, 0.0f), s);
        float ra = fmaxf(sdiff * depo, 0.0f);
        float rb = fmaxf((-sdiff) * diss, 0.0f);
        float deparg = fmaf(1.0f - ftb, ra - rb, first);
        float dep    = fmaxf(-fmaxf(hd, 0.0f), deparg);

        float s_new = s - dep;
        float t_new = t_c + dep;

        float rn = fmaxf(-fdy, 0.0f);
        float rm = fmaxf(1.0f - fabsf(fdy), 0.0f);
        float rp = fmaxf(fdy, 0.0f);

        float s1 = (c == WW - 1) ? 0.0f : rn * s_new;
        float s3 = (c == 0)      ? 0.0f : rp * s_new;
        sno[j] = fmaf(rm, s_new, s1) + s3;

        float w1 = (c == WW - 1) ? 0.0f : rn * w;
        float w3 = (c == 0)      ? 0.0f : rp * w;
        float wd = fmaf(rm, w, w1) + w3;
        wno[j] = wd * (1.0f - evapr);

        vno[j] = (gravr * hd) / CELLW;

        if (final_flag) {
            float aa = fmaf(-t_new, 2.0f, 1.0f);          // 1 - t*2 -> fnma
            float bq = 1.0f + aa;
            tno[j] = fmaxf(bq, 0.0f) - 1.0f;
        } else {
            tno[j] = t_new;
        }
    }

    *(float4*)(terr_out + idx0) = make_float4(tno[0], tno[1], tno[2], tno[3]);
    *(float4*)(sed + idx0)      = make_float4(sno[0], sno[1], sno[2], sno[3]);
    *(float4*)(wat + idx0)      = make_float4(wno[0], wno[1], wno[2], wno[3]);
    *(float4*)(vel + idx0)      = make_float4(vno[0], vno[1], vno[2], vno[3]);
}

extern "C" void kernel_launch(void* const* d_in, const int* in_sizes, int n_in,
                              void* d_out, int out_size, void* d_ws, size_t ws_size,
                              hipStream_t stream) {
    const float* in_terr    = (const float*)d_in[0];
    const float* rain_all   = (const float*)d_in[1];  // (1,10,W,W)
    const float* gnoise_all = (const float*)d_in[2];  // (1,10,W,W)
    const float* p_rr       = (const float*)d_in[3];
    const float* p_evap     = (const float*)d_in[4];
    const float* p_minhd    = (const float*)d_in[5];
    const float* p_heps     = (const float*)d_in[6];
    const float* p_grav     = (const float*)d_in[7];
    const float* p_scc      = (const float*)d_in[8];
    const float* p_diss     = (const float*)d_in[9];
    const float* p_depo     = (const float*)d_in[10];

    float* T0  = (float*)d_out;          // even-step source; final output
    float* ws  = (float*)d_ws;
    float* T1  = ws;
    float* sed = ws + (size_t)NTOT;
    float* wat = ws + (size_t)2 * NTOT;
    float* vel = ws + (size_t)3 * NTOT;

    dim3 block(256), grid(NTOT / 1024);  // 4 cells/thread

    // step 0: reads in_terr (transform on the fly), s/w/v = 0, writes T1
    erosion_step4<true><<<grid, block, 0, stream>>>(
        in_terr, T1, sed, wat, vel,
        rain_all, gnoise_all,
        p_rr, p_evap, p_minhd, p_heps, p_grav, p_scc, p_diss, p_depo, 0);

    for (int it = 1; it < 10; ++it) {
        const float* tin  = (it & 1) ? T1 : T0;
        float*       tout = (it & 1) ? T0 : T1;
        erosion_step4<false><<<grid, block, 0, stream>>>(
            tin, tout, sed, wat, vel,
            rain_all + (size_t)it * NPIX, gnoise_all + (size_t)it * NPIX,
            p_rr, p_evap, p_minhd, p_heps, p_grav, p_scc, p_diss, p_depo,
            (it == 9) ? 1 : 0);
    }
}

// Round 14
// 393.672 us; speedup vs baseline: 5.3779x; 1.0821x over previous
//
#include <hip/hip_runtime.h>

// ErosionLayer: B=16, W=512, ITERS=10, fp32. PASSING numeric recipe (r5..r13,
// absmax 0.02734375): XLA-style greedy FMA via explicit fmaf() at exact sites,
// contract(off) elsewhere, correctly-rounded fp32 div/sqrt. DO NOT change op
// order or fusion sites (cell_math is the frozen recipe).
//
// r14: 2-step fusion with halo recompute. Radius per step is [-1,+2] rows/cols
// (|fdx|,|fdy|<=1). Block owns 8 rows x 512 cols of one image; LDS A = terrain
// k-1 rows [r0-2, r1+4] (15x512), LDS B = terrain k computed over extended rows
// [r0-1, r1+2] (11x512); step-k s/w/v for owned rows in registers; step k+1
// computed for owned rows only. Per 2 steps this removes the intermediate
// terrain round-trip and half the s/w/v traffic (~136 -> ~70 MB/step HBM),
// and halves dispatch count. Bit-exact: every recomputed cell sees identical
// input bits; LDS round-trips preserve bits. FINAL skips dead s/w/v stores.
#pragma clang fp contract(off)

constexpr int WW   = 512;
constexpr int NPIX = WW * WW;      // 2^18
constexpr int NTOT = 16 * NPIX;    // 4194304
constexpr int HH   = 8;            // owned rows per block
constexpr int AR   = HH + 7;       // 15 LDS rows: [r0-2, r1+4]
constexpr int BR   = HH + 3;       // 11 LDS rows: [r0-1, r1+2]
constexpr int NBLK = 16 * (WW / HH);   // 1024

// FROZEN r5/r6 math; all terrain reads from an LDS tile with row offset.
__device__ __forceinline__ void cell_math(
    const float* __restrict__ lds, int rowOfs, int r, int c,
    float rain_v, float gno_v,
    float rr, float evapr, float minhd, float heps, float gravr, float sccr,
    float diss, float depo,
    float& s_io, float& w_io, float& v_io, float& t_out, bool fin)
{
    #pragma clang fp contract(off)
    const float CELLW = 0.390625f;            // 200/512, exact

    float t_c = lds[(r - rowOfs) * WW + c];

    float w = fmaf(rr, rain_v, w_io);

    float dx, dy;
    if      (r == 0)      dx = 0.5f * fmaf(t_c, 1.1f, -t_c);
    else if (r == WW - 1) dx = 0.5f * fmaf(t_c, 0.9f, -t_c);
    else dx = 0.5f * (lds[(r + 1 - rowOfs) * WW + c] - lds[(r - 1 - rowOfs) * WW + c]);
    if      (c == 0)      dy = 0.5f * fmaf(t_c, 1.1f, -t_c);
    else if (c == WW - 1) dy = 0.5f * fmaf(t_c, 0.9f, -t_c);
    else dy = 0.5f * (lds[(r - rowOfs) * WW + c + 1] - lds[(r - rowOfs) * WW + c - 1]);

    float mag = sqrtf(fmaf(dx, dx, dy * dy) + 1e-11f);
    float rX  = gno_v;
    float rY  = sqrtf(fmaf(-rX, rX, 1.0f));   // 1 - rX*rX -> fnma
    float factor = fmaxf(1e-10f - mag, 0.0f); // always 0; kept for fidelity
    float den = mag + factor;
    float fdx = fmaf(factor, rX, dx) / den;   // |fdx| <= 1
    float fdy = fmaf(factor, rY, dy) / den;   // |fdy| <= 1

    float fx  = (float)c + (-fdx);
    float fy  = (float)r + (-fdy);
    float x0f = floorf(fx), y0f = floorf(fy);
    float wx1 = fx - x0f;
    float wy1 = fy - y0f;
    int x0 = (int)x0f, y0 = (int)y0f;
    int x1 = x0 + 1,   y1 = y0 + 1;

    bool vx0 = (x0 >= 0) & (x0 < WW);
    bool vx1 = (x1 >= 0) & (x1 < WW);
    bool vy0 = (y0 >= 0) & (y0 < WW);
    bool vy1 = (y1 >= 0) & (y1 < WW);
    int x0c = min(max(x0, 0), WW - 1), x1c = min(max(x1, 0), WW - 1);
    int y0c = min(max(y0, 0), WW - 1), y1c = min(max(y1, 0), WW - 1);
    int ty0 = y0c - rowOfs, ty1 = y1c - rowOfs;   // within tile by radius proof

    float g00 = (vx0 && vy0) ? (lds[ty0 * WW + x0c] - 1.0f) : 0.0f;
    float g10 = (vx1 && vy0) ? (lds[ty0 * WW + x1c] - 1.0f) : 0.0f;
    float g01 = (vx0 && vy1) ? (lds[ty1 * WW + x0c] - 1.0f) : 0.0f;
    float g11 = (vx1 && vy1) ? (lds[ty1 * WW + x1c] - 1.0f) : 0.0f;

    float wx0 = 1.0f - wx1;
    float wy0 = 1.0f - wy1;
    float rowA = fmaf(wx0, g00, wx1 * g10);
    float rowB = fmaf(wx0, g01, wx1 * g11);
    float bil  = fmaf(wy0, rowA, wy1 * rowB);
    float neighbor = bil + 1.0f;

    float hd = t_c - neighbor;

    float v = v_io;
    float s = s_io;

    float hds  = ((hd - heps) > 0.0f) ? 1.0f : 0.0f;  // sign(relu(hd-eps))
    float nhd  = hds * fmaxf(hd, minhd);
    float q1 = nhd / CELLW;
    float q2 = q1 * v;
    float q3 = q2 * w;
    float sdiff = fmaf(-q3, sccr, s);                 // s - sed_cap
    float ftb   = (hd < 0.0f) ? 1.0f : 0.0f;          // relu(sign(-hd))
    float first = fminf(fmaxf(-hd, 0.0f), s);
    float ra = fmaxf(sdiff * depo, 0.0f);
    float rb = fmaxf((-sdiff) * diss, 0.0f);
    float deparg = fmaf(1.0f - ftb, ra - rb, first);
    float dep    = fmaxf(-fmaxf(hd, 0.0f), deparg);

    float s_new = s - dep;
    float t_new = t_c + dep;

    float rn = fmaxf(-fdy, 0.0f);
    float rm = fmaxf(1.0f - fabsf(fdy), 0.0f);
    float rp = fmaxf(fdy, 0.0f);

    float s1 = (c == WW - 1) ? 0.0f : rn * s_new;
    float s3 = (c == 0)      ? 0.0f : rp * s_new;
    s_io = fmaf(rm, s_new, s1) + s3;

    float w1 = (c == WW - 1) ? 0.0f : rn * w;
    float w3 = (c == 0)      ? 0.0f : rp * w;
    float wd = fmaf(rm, w, w1) + w3;
    w_io = wd * (1.0f - evapr);

    v_io = (gravr * hd) / CELLW;

    if (fin) {
        float aa = fmaf(-t_new, 2.0f, 1.0f);          // 1 - t*2 -> fnma
        float bq = 1.0f + aa;
        t_out = fmaxf(bq, 0.0f) - 1.0f;
    } else {
        t_out = t_new;
    }
}

template <bool FIRST, bool FINAL>
__global__ __launch_bounds__(512, 2) void erosion_fused(
    const float* __restrict__ tin, float* __restrict__ tout,
    float* __restrict__ sed, float* __restrict__ wat, float* __restrict__ vel,
    const float* __restrict__ rain0, const float* __restrict__ gno0,
    const float* __restrict__ rain1, const float* __restrict__ gno1,
    const float* __restrict__ s_rain_rate, const float* __restrict__ s_evap,
    const float* __restrict__ s_minhd, const float* __restrict__ s_heps,
    const float* __restrict__ s_grav, const float* __restrict__ s_scc,
    const float* __restrict__ s_diss, const float* __restrict__ s_depo)
{
    #pragma clang fp contract(off)
    __shared__ float A[AR * WW];    // terrain k-1, rows [r0-2, r1+4]
    __shared__ float B[BR * WW];    // terrain k,   rows [r0-1, r1+2]

    const int c   = threadIdx.x;
    const int img = blockIdx.x >> 6;           // 64 tiles per image
    const int r0  = (blockIdx.x & 63) * HH;
    const float* tb = tin + (size_t)img * NPIX;

    float rr    = fmaxf(s_rain_rate[0], 0.0f);
    float evapr = fmaxf(s_evap[0], 0.0f);
    float minhd = s_minhd[0];
    float heps  = s_heps[0];
    float gravr = fmaxf(s_grav[0], 0.0f);
    float sccr  = fmaxf(s_scc[0], 0.0f);
    float diss  = s_diss[0];
    float depo  = s_depo[0];

    // ---- stage terrain k-1 (transform on the fly if FIRST) ----
    #pragma unroll
    for (int i = 0; i < AR; ++i) {
        int y = r0 - 2 + i;
        if (y >= 0 && y < WW) {
            float v = tb[y * WW + c];
            if (FIRST) v = (1.0f - v) / 2.0f;
            A[i * WW + c] = v;
        }
    }
    __syncthreads();

    // ---- phase 1: step k over extended rows [r0-1, r1+2] ----
    float sK[HH], wK[HH], vK[HH];
    #pragma unroll
    for (int i = 0; i < BR; ++i) {
        int x = r0 - 1 + i;
        if (x >= 0 && x < WW) {
            float s0, w0, v0;
            if (FIRST) { s0 = 0.0f; w0 = 0.0f; v0 = 0.0f; }
            else {
                int g = img * NPIX + x * WW + c;
                s0 = sed[g]; w0 = wat[g]; v0 = vel[g];
            }
            float tn;
            cell_math(A, r0 - 2, x, c, rain0[x * WW + c], gno0[x * WW + c],
                      rr, evapr, minhd, heps, gravr, sccr, diss, depo,
                      s0, w0, v0, tn, false);
            B[i * WW + c] = tn;
            if (i >= 1 && i <= HH) {            // owned rows: j = i-1 (constant)
                sK[i - 1] = s0; wK[i - 1] = w0; vK[i - 1] = v0;
            }
        }
    }
    __syncthreads();

    // ---- phase 2: step k+1 over owned rows ----
    #pragma unroll
    for (int j = 0; j < HH; ++j) {
        int x = r0 + j;
        float s0 = sK[j], w0 = wK[j], v0 = vK[j];
        float tn;
        cell_math(B, r0 - 1, x, c, rain1[x * WW + c], gno1[x * WW + c],
                  rr, evapr, minhd, heps, gravr, sccr, diss, depo,
                  s0, w0, v0, tn, FINAL);
        int g = img * NPIX + x * WW + c;
        tout[g] = tn;
        if (!FINAL) { sed[g] = s0; wat[g] = w0; vel[g] = v0; }
    }
}

extern "C" void kernel_launch(void* const* d_in, const int* in_sizes, int n_in,
                              void* d_out, int out_size, void* d_ws, size_t ws_size,
                              hipStream_t stream) {
    const float* in_terr    = (const float*)d_in[0];
    const float* rain_all   = (const float*)d_in[1];  // (1,10,W,W)
    const float* gnoise_all = (const float*)d_in[2];  // (1,10,W,W)
    const float* p_rr       = (const float*)d_in[3];
    const float* p_evap     = (const float*)d_in[4];
    const float* p_minhd    = (const float*)d_in[5];
    const float* p_heps     = (const float*)d_in[6];
    const float* p_grav     = (const float*)d_in[7];
    const float* p_scc      = (const float*)d_in[8];
    const float* p_diss     = (const float*)d_in[9];
    const float* p_depo     = (const float*)d_in[10];

    float* T0  = (float*)d_out;          // final output
    float* ws  = (float*)d_ws;
    float* T1  = ws;
    float* T2  = ws + (size_t)NTOT;
    float* sed = ws + (size_t)2 * NTOT;
    float* wat = ws + (size_t)3 * NTOT;
    float* vel = ws + (size_t)4 * NTOT;

    dim3 grid(NBLK), block(512);
    #define RN(k) (rain_all   + (size_t)(k) * NPIX)
    #define GN(k) (gnoise_all + (size_t)(k) * NPIX)
    #define SCAL p_rr, p_evap, p_minhd, p_heps, p_grav, p_scc, p_diss, p_depo

    // steps 0+1: in_terr (transform on the fly) -> T1
    erosion_fused<true, false><<<grid, block, 0, stream>>>(
        in_terr, T1, sed, wat, vel, RN(0), GN(0), RN(1), GN(1), SCAL);
    // steps 2+3: T1 -> T2
    erosion_fused<false, false><<<grid, block, 0, stream>>>(
        T1, T2, sed, wat, vel, RN(2), GN(2), RN(3), GN(3), SCAL);
    // steps 4+5: T2 -> T1
    erosion_fused<false, false><<<grid, block, 0, stream>>>(
        T2, T1, sed, wat, vel, RN(4), GN(4), RN(5), GN(5), SCAL);
    // steps 6+7: T1 -> T2
    erosion_fused<false, false><<<grid, block, 0, stream>>>(
        T1, T2, sed, wat, vel, RN(6), GN(6), RN(7), GN(7), SCAL);
    // steps 8+9: T2 -> T0 (= d_out), final transform, skip dead s/w/v stores
    erosion_fused<false, true><<<grid, block, 0, stream>>>(
        T2, T0, sed, wat, vel, RN(8), GN(8), RN(9), GN(9), SCAL);

    #undef RN
    #undef GN
    #undef SCAL
}